// Round 3
// baseline (6698.093 us; speedup 1.0000x reference)
//
#include <hip/hip_runtime.h>
#include <hip/hip_bf16.h>

// Problem constants
#define NROWS 16384
#define CDIM  512
#define KNB   10
#define TAU_INV 20.0f

// topk kernel tiling
constexpr int TX   = 32;    // x rows per block
constexpr int TYC  = 512;   // y cols per tile
constexpr int KC   = 32;    // k chunk staged in LDS
constexpr int PADK = 36;    // LDS row stride (floats); 144B row = 16B-aligned, breaks pow2
constexpr int SIMPAD = 516; // sim tile row stride (floats)

// ---------------- kernel 1: inverse L2 norms ----------------
__global__ __launch_bounds__(64) void norms_kernel(const float* __restrict__ X,
                                                   const float* __restrict__ Y,
                                                   float* __restrict__ inv) {
    int b = blockIdx.x;
    const float* src = (b < NROWS) ? X : Y;
    int row = (b < NROWS) ? b : b - NROWS;
    const float4* p = reinterpret_cast<const float4*>(src + (size_t)row * CDIM);
    int t = threadIdx.x; // 64 threads = 1 wave
    float ss = 0.f;
    #pragma unroll
    for (int i = 0; i < CDIM / 4 / 64; ++i) {
        float4 v = p[t + i * 64];
        ss += v.x * v.x + v.y * v.y + v.z * v.z + v.w * v.w;
    }
    #pragma unroll
    for (int off = 32; off; off >>= 1) ss += __shfl_xor(ss, off, 64);
    if (t == 0) inv[b] = 1.0f / fmaxf(sqrtf(ss), 1e-12f);
}

// stable top-k comparator: matches jax.lax.top_k (desc values, asc index on ties)
__device__ __forceinline__ bool better(float v1, int i1, float v2, int i2) {
    return (v1 > v2) || (v1 == v2 && i1 < i2);
}

// ---------------- kernel 2: sim + streaming top-10 + softmax ----------------
// Numerics contract: per (row,col), sims accumulate with fmaf over k strictly
// ascending (kc asc, kq asc, then x,y,z,w) — bit-identical to the R1-passing
// kernel. DO NOT reorder (near-tie top-k flips vs the np reference otherwise).
__global__ __launch_bounds__(256, 2) void topk_kernel(const float* __restrict__ X,
                                                      const float* __restrict__ Y,
                                                      const float* __restrict__ invx,
                                                      const float* __restrict__ invy,
                                                      float* __restrict__ out) {
    __shared__ float xs[TX][PADK];       // 4608 B
    __shared__ float smem[TYC * PADK];   // 73728 B; reused as sim[32][516] and cand buffers

    const int t = threadIdx.x;
    const int rowBase = blockIdx.x * TX;
    const int tx = t & 31;               // col lane
    const int ty2 = t >> 5;              // 0..7
    const int rg = ty2 & 3;              // row group: rows rg*8 + m
    const int ch = ty2 >> 2;             // col half: cols tx + 32n + 256*ch
    const int rs = t >> 3, sl = t & 7;   // scan mapping: row rs, slot sl (cols ≡ sl mod 8)

    // register-resident running top-10 for row (rowBase+rs), columns sl+8k pattern
    float tv[KNB];
    int   tix[KNB];
    #pragma unroll
    for (int j = 0; j < KNB; ++j) { tv[j] = -1e30f; tix[j] = 0x7fffffff; }

    const float4* X4 = reinterpret_cast<const float4*>(X);
    const float4* Y4 = reinterpret_cast<const float4*>(Y);

    for (int tile = 0; tile < NROWS / TYC; ++tile) {   // 32 tiles
        const int colBase = tile * TYC;
        float acc[8][8];
        #pragma unroll
        for (int m = 0; m < 8; ++m)
            #pragma unroll
            for (int n = 0; n < 8; ++n) acc[m][n] = 0.f;

        for (int kc = 0; kc < CDIM / KC; ++kc) {       // 16 chunks
            const int kq0 = kc * (KC / 4);
            __syncthreads(); // previous use of smem (ys or sim scan) done

            // stage x chunk: 32 rows x 32 floats = 256 float4, 1/thread
            {
                int lrow = t >> 3, lq = t & 7;
                float s = invx[rowBase + lrow];
                float4 v = X4[(size_t)(rowBase + lrow) * (CDIM / 4) + kq0 + lq];
                *reinterpret_cast<float4*>(&xs[lrow][lq * 4]) =
                    make_float4(v.x * s, v.y * s, v.z * s, v.w * s);
            }
            // stage y chunk: 512 rows x 32 floats = 4096 float4, 16/thread
            #pragma unroll
            for (int it = 0; it < 16; ++it) {
                int l = t + 256 * it;
                int lrow = l >> 3, lq = l & 7;
                float s = invy[colBase + lrow];
                float4 v = Y4[(size_t)(colBase + lrow) * (CDIM / 4) + kq0 + lq];
                *reinterpret_cast<float4*>(&smem[lrow * PADK + lq * 4]) =
                    make_float4(v.x * s, v.y * s, v.z * s, v.w * s);
            }
            __syncthreads();

            // inner product: 8x8 register block, b128 LDS reads, 4 k per group
            #pragma unroll
            for (int kq = 0; kq < KC / 4; ++kq) {
                float4 a[8];
                #pragma unroll
                for (int m = 0; m < 8; ++m)
                    a[m] = *reinterpret_cast<const float4*>(&xs[rg * 8 + m][kq * 4]);
                #pragma unroll
                for (int n = 0; n < 8; ++n) {
                    float4 b = *reinterpret_cast<const float4*>(
                        &smem[(tx + 32 * n + 256 * ch) * PADK + kq * 4]);
                    #pragma unroll
                    for (int m = 0; m < 8; ++m) {
                        // sequential x,y,z,w — preserves R1 bit-exact k-order
                        acc[m][n] = fmaf(a[m].x, b.x, acc[m][n]);
                        acc[m][n] = fmaf(a[m].y, b.y, acc[m][n]);
                        acc[m][n] = fmaf(a[m].z, b.z, acc[m][n]);
                        acc[m][n] = fmaf(a[m].w, b.w, acc[m][n]);
                    }
                }
            }
        }

        // dump C tile to LDS (reuse ys region as sim[32][SIMPAD])
        __syncthreads(); // all waves done reading ys
        #pragma unroll
        for (int m = 0; m < 8; ++m)
            #pragma unroll
            for (int n = 0; n < 8; ++n)
                smem[(rg * 8 + m) * SIMPAD + tx + 32 * n + 256 * ch] = acc[m][n];
        __syncthreads();

        // scan: 8 threads per row, thread sl covers cols sl+8k (same partition as R1)
        for (int k = 0; k < TYC / 8; ++k) {
            float v = smem[rs * SIMPAD + sl + 8 * k];
            int col = colBase + sl + 8 * k;
            if (better(v, col, tv[KNB - 1], tix[KNB - 1])) {
                tv[KNB - 1] = v; tix[KNB - 1] = col;
                #pragma unroll
                for (int j = KNB - 1; j > 0; --j) {
                    if (better(tv[j], tix[j], tv[j - 1], tix[j - 1])) {
                        float fv = tv[j]; tv[j] = tv[j - 1]; tv[j - 1] = fv;
                        int fi = tix[j]; tix[j] = tix[j - 1]; tix[j - 1] = fi;
                    }
                }
            }
        }
        // loop top's __syncthreads() protects sim before next ys staging
    }

    // -------- final merge: 8 candidate lists -> top-10 per row --------
    __syncthreads();
    float* cv = smem;                                   // [32][80] floats
    int*   ci = reinterpret_cast<int*>(smem + TX * 80); // [32][80] ints
    #pragma unroll
    for (int j = 0; j < KNB; ++j) {
        cv[rs * 80 + sl * KNB + j] = tv[j];
        ci[rs * 80 + sl * KNB + j] = tix[j];
    }
    __syncthreads();

    if (t < TX) {
        float mv[KNB]; int mi[KNB];
        #pragma unroll
        for (int j = 0; j < KNB; ++j) { mv[j] = -1e30f; mi[j] = 0x7fffffff; }
        for (int c = 0; c < 80; ++c) {
            float v = cv[t * 80 + c];
            int   id = ci[t * 80 + c];
            if (better(v, id, mv[KNB - 1], mi[KNB - 1])) {
                mv[KNB - 1] = v; mi[KNB - 1] = id;
                #pragma unroll
                for (int j = KNB - 1; j > 0; --j) {
                    if (better(mv[j], mi[j], mv[j - 1], mi[j - 1])) {
                        float fv = mv[j]; mv[j] = mv[j - 1]; mv[j - 1] = fv;
                        int fi = mi[j]; mi[j] = mi[j - 1]; mi[j - 1] = fi;
                    }
                }
            }
        }
        // softmax over mv/tau (shift by max = mv[0], list is sorted desc)
        float mmax = mv[0];
        float e[KNB]; float sum = 0.f;
        #pragma unroll
        for (int j = 0; j < KNB; ++j) { e[j] = expf((mv[j] - mmax) * TAU_INV); sum += e[j]; }

        const size_t gr = (size_t)rowBase + t;
        #pragma unroll
        for (int j = 0; j < KNB; ++j) {
            out[gr * KNB + j] = e[j] / sum;                                  // values
            out[(size_t)NROWS * KNB + gr * KNB + j] = (float)gr;             // indices[0] (rows)
            out[(size_t)2 * NROWS * KNB + gr * KNB + j] = (float)mi[j];      // indices[1] (cols)
        }
    }
}

extern "C" void kernel_launch(void* const* d_in, const int* in_sizes, int n_in,
                              void* d_out, int out_size, void* d_ws, size_t ws_size,
                              hipStream_t stream) {
    const float* X = (const float*)d_in[0];
    const float* Y = (const float*)d_in[1];
    float* inv = (float*)d_ws;              // [0,16384): invx, [16384,32768): invy
    float* out = (float*)d_out;

    norms_kernel<<<2 * NROWS, 64, 0, stream>>>(X, Y, inv);
    topk_kernel<<<NROWS / TX, 256, 0, stream>>>(X, Y, inv, inv + NROWS, out);
}

// Round 4
// 6157.271 us; speedup vs baseline: 1.0878x; 1.0878x over previous
//
#include <hip/hip_runtime.h>
#include <hip/hip_bf16.h>

// Problem constants
#define NROWS 16384
#define CDIM  512
#define KNB   10
#define TAU_INV 20.0f

// topk kernel tiling
constexpr int TX   = 32;    // x rows per block
constexpr int TYC  = 512;   // y cols per tile
constexpr int KC   = 32;    // k chunk staged in LDS
constexpr int PADK = 36;    // LDS row stride (floats); 144B row = 16B-aligned, breaks pow2
constexpr int SIMPAD = 516; // sim tile row stride (floats)

// ---------------- kernel 1: inverse L2 norms ----------------
__global__ __launch_bounds__(64) void norms_kernel(const float* __restrict__ X,
                                                   const float* __restrict__ Y,
                                                   float* __restrict__ inv) {
    int b = blockIdx.x;
    const float* src = (b < NROWS) ? X : Y;
    int row = (b < NROWS) ? b : b - NROWS;
    const float4* p = reinterpret_cast<const float4*>(src + (size_t)row * CDIM);
    int t = threadIdx.x; // 64 threads = 1 wave
    float ss = 0.f;
    #pragma unroll
    for (int i = 0; i < CDIM / 4 / 64; ++i) {
        float4 v = p[t + i * 64];
        ss += v.x * v.x + v.y * v.y + v.z * v.z + v.w * v.w;
    }
    #pragma unroll
    for (int off = 32; off; off >>= 1) ss += __shfl_xor(ss, off, 64);
    if (t == 0) inv[b] = 1.0f / fmaxf(sqrtf(ss), 1e-12f);
}

// stable top-k comparator: matches jax.lax.top_k (desc values, asc index on ties)
__device__ __forceinline__ bool better(float v1, int i1, float v2, int i2) {
    return (v1 > v2) || (v1 == v2 && i1 < i2);
}

// ---------------- kernel 2: sim + per-slice top-10 ----------------
// Numerics contract: per (row,col), sims accumulate with fmaf over k strictly
// ascending (kc asc, kq asc, then x,y,z,w) — bit-identical to the R1-passing
// kernel. DO NOT reorder (near-tie top-k flips vs the np reference otherwise).
// Slicing only changes WHICH block computes a column — per-element bits identical.
template<int NSLICES>
__global__ __launch_bounds__(256, 2) void topk_kernel(const float* __restrict__ X,
                                                      const float* __restrict__ Y,
                                                      const float* __restrict__ invx,
                                                      const float* __restrict__ invy,
                                                      float* __restrict__ oval,
                                                      int* __restrict__ oidx) {
    constexpr int SLICE_COLS = NROWS / NSLICES;
    constexpr int NTILES = SLICE_COLS / TYC;

    __shared__ float xs[TX][PADK];       // 4608 B
    __shared__ float smem[TYC * PADK];   // 73728 B; reused as sim[32][516] and cand buffers

    const int t = threadIdx.x;

    // block -> (rowBlock, slice): slice pinned to one XCD (blockIdx round-robins XCDs)
    int rowBlock, slice;
    if (NSLICES == 16) {
        int g = blockIdx.x & 7, j = blockIdx.x >> 3;
        slice = g + 8 * (j >> 9);   // first 512 j's on XCD g do slice g, then g+8
        rowBlock = j & 511;
    } else {
        slice = 0; rowBlock = blockIdx.x;
    }
    const int rowBase = rowBlock * TX;
    const int sliceBase = slice * SLICE_COLS;

    const int tx = t & 31;               // col lane
    const int ty2 = t >> 5;              // 0..7
    const int rg = ty2 & 3;              // row group: rows rg*8 + m
    const int ch = ty2 >> 2;             // col half: cols tx + 32n + 256*ch
    const int rs = t >> 3, sl = t & 7;   // scan mapping: row rs, slot sl (cols ≡ sl mod 8)

    // register-resident running top-10 for row (rowBase+rs), columns ≡ sl (mod 8)
    float tv[KNB];
    int   tix[KNB];
    #pragma unroll
    for (int j = 0; j < KNB; ++j) { tv[j] = -1e30f; tix[j] = 0x7fffffff; }

    const float4* X4 = reinterpret_cast<const float4*>(X);
    const float4* Y4 = reinterpret_cast<const float4*>(Y);

    const float sx = invx[rowBase + (t >> 3)];   // x-stage scale (constant per block)

    for (int tile = 0; tile < NTILES; ++tile) {
        const int colBase = sliceBase + tile * TYC;

        // hoist invy for the 16 staging rows this thread touches (same values as per-kc loads)
        float sy[16];
        #pragma unroll
        for (int it = 0; it < 16; ++it) sy[it] = invy[colBase + ((t + 256 * it) >> 3)];

        float acc[8][8];
        #pragma unroll
        for (int m = 0; m < 8; ++m)
            #pragma unroll
            for (int n = 0; n < 8; ++n) acc[m][n] = 0.f;

        for (int kc = 0; kc < CDIM / KC; ++kc) {       // 16 chunks
            const int kq0 = kc * (KC / 4);
            __syncthreads(); // previous use of smem (ys or sim scan) done

            // stage x chunk: 32 rows x 32 floats = 256 float4, 1/thread
            {
                int lrow = t >> 3, lq = t & 7;
                float4 v = X4[(size_t)(rowBase + lrow) * (CDIM / 4) + kq0 + lq];
                *reinterpret_cast<float4*>(&xs[lrow][lq * 4]) =
                    make_float4(v.x * sx, v.y * sx, v.z * sx, v.w * sx);
            }
            // stage y chunk: 512 rows x 32 floats = 4096 float4, 16/thread
            #pragma unroll
            for (int it = 0; it < 16; ++it) {
                int l = t + 256 * it;
                int lrow = l >> 3, lq = l & 7;
                float s = sy[it];
                float4 v = Y4[(size_t)(colBase + lrow) * (CDIM / 4) + kq0 + lq];
                *reinterpret_cast<float4*>(&smem[lrow * PADK + lq * 4]) =
                    make_float4(v.x * s, v.y * s, v.z * s, v.w * s);
            }
            __syncthreads();

            // inner product: 8x8 register block, b128 LDS reads, 4 k per group
            #pragma unroll
            for (int kq = 0; kq < KC / 4; ++kq) {
                float4 a[8];
                #pragma unroll
                for (int m = 0; m < 8; ++m)
                    a[m] = *reinterpret_cast<const float4*>(&xs[rg * 8 + m][kq * 4]);
                #pragma unroll
                for (int n = 0; n < 8; ++n) {
                    float4 b = *reinterpret_cast<const float4*>(
                        &smem[(tx + 32 * n + 256 * ch) * PADK + kq * 4]);
                    #pragma unroll
                    for (int m = 0; m < 8; ++m) {
                        // sequential x,y,z,w — preserves R1 bit-exact k-order
                        acc[m][n] = fmaf(a[m].x, b.x, acc[m][n]);
                        acc[m][n] = fmaf(a[m].y, b.y, acc[m][n]);
                        acc[m][n] = fmaf(a[m].z, b.z, acc[m][n]);
                        acc[m][n] = fmaf(a[m].w, b.w, acc[m][n]);
                    }
                }
            }
        }

        // dump C tile to LDS (reuse ys region as sim[32][SIMPAD])
        __syncthreads(); // all waves done reading ys
        #pragma unroll
        for (int m = 0; m < 8; ++m)
            #pragma unroll
            for (int n = 0; n < 8; ++n)
                smem[(rg * 8 + m) * SIMPAD + tx + 32 * n + 256 * ch] = acc[m][n];
        __syncthreads();

        // scan: 8 threads per row, thread sl covers cols sl+8k
        for (int k = 0; k < TYC / 8; ++k) {
            float v = smem[rs * SIMPAD + sl + 8 * k];
            int col = colBase + sl + 8 * k;
            if (better(v, col, tv[KNB - 1], tix[KNB - 1])) {
                tv[KNB - 1] = v; tix[KNB - 1] = col;
                #pragma unroll
                for (int j = KNB - 1; j > 0; --j) {
                    if (better(tv[j], tix[j], tv[j - 1], tix[j - 1])) {
                        float fv = tv[j]; tv[j] = tv[j - 1]; tv[j - 1] = fv;
                        int fi = tix[j]; tix[j] = tix[j - 1]; tix[j - 1] = fi;
                    }
                }
            }
        }
        // loop top's __syncthreads() protects sim before next ys staging
    }

    // -------- per-block merge: 8 candidate lists -> top-10 per row, write to ws --------
    __syncthreads();
    float* cv = smem;                                   // [32][80] floats
    int*   ci = reinterpret_cast<int*>(smem + TX * 80); // [32][80] ints
    #pragma unroll
    for (int j = 0; j < KNB; ++j) {
        cv[rs * 80 + sl * KNB + j] = tv[j];
        ci[rs * 80 + sl * KNB + j] = tix[j];
    }
    __syncthreads();

    if (t < TX) {
        float mv[KNB]; int mi[KNB];
        #pragma unroll
        for (int j = 0; j < KNB; ++j) { mv[j] = -1e30f; mi[j] = 0x7fffffff; }
        for (int c = 0; c < 80; ++c) {
            float v = cv[t * 80 + c];
            int   id = ci[t * 80 + c];
            if (better(v, id, mv[KNB - 1], mi[KNB - 1])) {
                mv[KNB - 1] = v; mi[KNB - 1] = id;
                #pragma unroll
                for (int j = KNB - 1; j > 0; --j) {
                    if (better(mv[j], mi[j], mv[j - 1], mi[j - 1])) {
                        float fv = mv[j]; mv[j] = mv[j - 1]; mv[j - 1] = fv;
                        int fi = mi[j]; mi[j] = mi[j - 1]; mi[j - 1] = fi;
                    }
                }
            }
        }
        const size_t base = ((size_t)(rowBase + t) * NSLICES + slice) * KNB;
        #pragma unroll
        for (int j = 0; j < KNB; ++j) { oval[base + j] = mv[j]; oidx[base + j] = mi[j]; }
    }
}

// ---------------- kernel 3: exact merge of per-slice top-10s + softmax ----------------
__global__ __launch_bounds__(256) void merge_kernel(const float* __restrict__ oval,
                                                    const int* __restrict__ oidx,
                                                    float* __restrict__ out,
                                                    int nsl) {
    int r = blockIdx.x * 256 + threadIdx.x;
    if (r >= NROWS) return;

    float mv[KNB]; int mi[KNB];
    #pragma unroll
    for (int j = 0; j < KNB; ++j) { mv[j] = -1e30f; mi[j] = 0x7fffffff; }

    const size_t rb = (size_t)r * nsl * KNB;
    for (int c = 0; c < nsl * KNB; ++c) {
        float v = oval[rb + c];
        int   id = oidx[rb + c];
        if (better(v, id, mv[KNB - 1], mi[KNB - 1])) {
            mv[KNB - 1] = v; mi[KNB - 1] = id;
            #pragma unroll
            for (int j = KNB - 1; j > 0; --j) {
                if (better(mv[j], mi[j], mv[j - 1], mi[j - 1])) {
                    float fv = mv[j]; mv[j] = mv[j - 1]; mv[j - 1] = fv;
                    int fi = mi[j]; mi[j] = mi[j - 1]; mi[j - 1] = fi;
                }
            }
        }
    }

    // softmax over mv/tau (shift by max = mv[0], list is sorted desc)
    float mmax = mv[0];
    float e[KNB]; float sum = 0.f;
    #pragma unroll
    for (int j = 0; j < KNB; ++j) { e[j] = expf((mv[j] - mmax) * TAU_INV); sum += e[j]; }

    const size_t gr = (size_t)r;
    #pragma unroll
    for (int j = 0; j < KNB; ++j) {
        out[gr * KNB + j] = e[j] / sum;                                  // values
        out[(size_t)NROWS * KNB + gr * KNB + j] = (float)gr;             // indices[0] (rows)
        out[(size_t)2 * NROWS * KNB + gr * KNB + j] = (float)mi[j];      // indices[1] (cols)
    }
}

extern "C" void kernel_launch(void* const* d_in, const int* in_sizes, int n_in,
                              void* d_out, int out_size, void* d_ws, size_t ws_size,
                              hipStream_t stream) {
    const float* X = (const float*)d_in[0];
    const float* Y = (const float*)d_in[1];
    float* inv = (float*)d_ws;              // [0,16384): invx, [16384,32768): invy
    float* out = (float*)d_out;

    norms_kernel<<<2 * NROWS, 64, 0, stream>>>(X, Y, inv);

    float* vals = inv + 2 * NROWS;
    // 16-slice path needs: norms 128KB + vals 10.5MB + idxs 10.5MB
    const size_t need16 = (size_t)2 * NROWS * 4
                        + (size_t)NROWS * 16 * KNB * 4 * 2;
    if (ws_size >= need16) {
        int* idxs = (int*)(vals + (size_t)NROWS * 16 * KNB);
        topk_kernel<16><<<512 * 16, 256, 0, stream>>>(X, Y, inv, inv + NROWS, vals, idxs);
        merge_kernel<<<NROWS / 256, 256, 0, stream>>>(vals, idxs, out, 16);
    } else {
        int* idxs = (int*)(vals + (size_t)NROWS * KNB);
        topk_kernel<1><<<512, 256, 0, stream>>>(X, Y, inv, inv + NROWS, vals, idxs);
        merge_kernel<<<NROWS / 256, 256, 0, stream>>>(vals, idxs, out, 1);
    }
}